// Round 5
// baseline (37278.027 us; speedup 1.0000x reference)
//
#include <hip/hip_runtime.h>
#include <math.h>

// Sinkhorn OT layer, B=8192, C=256, L=100, LAMBD=1.
//
// U = log_u - ||x_i||^2, V = log_v - ||y_j||^2, G[i][j] = 2*dot(x_i,y_j):
//   U[i] = -LSE_j(G[i][j] + V[j]),  V[j] = -LSE_i(G[i][j] + U[i])
// init V[j] = -||y_j||^2. Final: out[i] = y[argmax_j(G[i][j]+V[j])].
//
// R6: int24 G (Glo u16 128 MiB + Ghi s8 64 MiB). 7498 us.
// R7/R9: fused row+col, re-read from cache. 9094/8056 us -- FAILED because
// the re-read window (768 KiB/block) spilled L2 (24 MiB/XCD in flight) and
// L3 gives no BW amplification (~6 TB/s effective either way).
// R10: shrink the re-read window to the WAVE's own 2 rows (48 KiB, just
// streamed -> L2-hot; 64 blocks/XCD x 48 KiB = 3 MiB < 4 MiB L2):
//  - wave owns rows 2w,2w+1: online (m,s) in-wave, butterfly, W0/W1 stay
//    in REGISTERS (no W_lds, no mid barrier).
//  - wave immediately re-reads its own rows, P = exp(G+V-W) in [0,1],
//    atomicAdd into block csum LDS. csum is XOR-swizzled
//    js = j ^ ((j>>6)&7) -> every atomic step hits 2 lanes/bank (free),
//    with p[k] statically indexed (no scratch).
//  - 512-thr blocks (8 waves, RPB=16), grid 512 = 2 blocks/CU, LDS 64 KiB.
//  - 2 barriers per dispatch (post-zero, pre-writeout).
// Per-iter HBM: ~400 MiB -> ~240 MiB (G once + 32 MiB partials + V).
//
// Kept: int24 G (q=2^-15), conflict-free f32 GEMM, combine clamp
// (all-underflow cols, self-correcting), smallest-index argmax tie-break.

#define B 8192
#define C 256
#define LITERS 100
#define RPB 16                     // rows per fused block = 8 waves x 2
#define NCH (B / RPB)              // 512 partial chunks

#define QS 65536.0f                // (2*acc) * 32768 == acc * 65536
#define QI 3.0517578125e-5f        // 2^-15

typedef float f32x4 __attribute__((ext_vector_type(4)));
typedef unsigned short u16x8 __attribute__((ext_vector_type(8)));
typedef signed char i8x8 __attribute__((ext_vector_type(8)));

__device__ __align__(16) float g_V[B];

// ---------------- init: V[j] = -||y_j||^2 ----------------
__global__ __launch_bounds__(256) void init_V(const float* __restrict__ y) {
    int wave = threadIdx.x >> 6;
    int lane = threadIdx.x & 63;
    int row = blockIdx.x * 4 + wave;
    const f32x4* yr = (const f32x4*)(y + (size_t)row * C);
    f32x4 v = yr[lane];
    float s = v.x * v.x + v.y * v.y + v.z * v.z + v.w * v.w;
    #pragma unroll
    for (int off = 32; off; off >>= 1) s += __shfl_down(s, off, 64);
    if (lane == 0) g_V[row] = -s;
}

// ---------------- GEMM: G = 2 * x @ y^T, quantized to int24 ----------------
#define GT 64
#define GKT 64
#define LSTR (GKT + 4)   // 68 floats; float4-aligned offsets

__global__ __launch_bounds__(256) void gemm_G(const float* __restrict__ x,
                                              const float* __restrict__ y,
                                              unsigned short* __restrict__ Glo,
                                              signed char* __restrict__ Ghi) {
    __shared__ float As[GT][LSTR];   // [i][k]
    __shared__ float Bs[GT][LSTR];   // [j][k]
    int bi = blockIdx.y * GT;
    int bj = blockIdx.x * GT;
    int t = threadIdx.x;
    int tx = t & 15, ty = t >> 4;
    float acc[4][4] = {};
    for (int kk = 0; kk < C; kk += GKT) {
        #pragma unroll
        for (int l = 0; l < 4; ++l) {
            int idx = t + l * 256;         // float4 index in tile
            int r = idx >> 4;              // tile row 0..63
            int c4 = idx & 15;             // float4 col 0..15
            *(f32x4*)&As[r][c4 * 4] =
                *(const f32x4*)(x + (size_t)(bi + r) * C + kk + c4 * 4);
            *(f32x4*)&Bs[r][c4 * 4] =
                *(const f32x4*)(y + (size_t)(bj + r) * C + kk + c4 * 4);
        }
        __syncthreads();
        #pragma unroll
        for (int k4 = 0; k4 < GKT / 4; ++k4) {
            f32x4 a[4], b[4];
            #pragma unroll
            for (int ii = 0; ii < 4; ++ii)
                a[ii] = *(const f32x4*)&As[ty * 4 + ii][k4 * 4];
            #pragma unroll
            for (int jj = 0; jj < 4; ++jj)
                b[jj] = *(const f32x4*)&Bs[tx + 16 * jj][k4 * 4];
            #pragma unroll
            for (int ii = 0; ii < 4; ++ii)
                #pragma unroll
                for (int jj = 0; jj < 4; ++jj) {
                    acc[ii][jj] = fmaf(a[ii].x, b[jj].x, acc[ii][jj]);
                    acc[ii][jj] = fmaf(a[ii].y, b[jj].y, acc[ii][jj]);
                    acc[ii][jj] = fmaf(a[ii].z, b[jj].z, acc[ii][jj]);
                    acc[ii][jj] = fmaf(a[ii].w, b[jj].w, acc[ii][jj]);
                }
        }
        __syncthreads();
    }
    #pragma unroll
    for (int ii = 0; ii < 4; ++ii) {
        int gi = bi + ty * 4 + ii;
        #pragma unroll
        for (int jj = 0; jj < 4; ++jj) {
            size_t idx = (size_t)gi * B + bj + tx + 16 * jj;
            float gs = acc[ii][jj] * QS;                       // G * 2^15
            gs = fminf(fmaxf(gs, -8388607.0f), 8388607.0f);    // int24 clamp
            int v = __float2int_rn(gs);
            Glo[idx] = (unsigned short)(v & 0xFFFF);
            Ghi[idx] = (signed char)(v >> 16);
        }
    }
}

// ---------------- fused row+col pass ----------------
// Block = 512 threads (8 waves), owns rows [chunk*16, chunk*16+16).
// Wave w: rows i0+2w, i0+2w+1. Phase 1: online (m,s), butterfly -> W in
// regs. Phase 2: re-read own rows (L2-hot), atomicAdd P into swizzled csum.
__global__ __launch_bounds__(512, 4) void fused_iter(
        const unsigned short* __restrict__ Glo,
        const signed char* __restrict__ Ghi,
        float* __restrict__ pm) {
    __shared__ float V_lds[B];        // 32 KiB, linear
    __shared__ float csum[B];         // 32 KiB, swizzled js = j ^ ((j>>6)&7)
    int t = threadIdx.x;
    int chunk = blockIdx.x;
    int i0 = chunk * RPB;
    int wave = t >> 6, lane = t & 63;

    // ---- stage V (linear) + zero csum (zero is swizzle-invariant) ----
    #pragma unroll
    for (int k = 0; k < 4; ++k) {
        int fi = 2048 * k + 4 * t;
        *(f32x4*)&V_lds[fi] = *(const f32x4*)&g_V[fi];
        *(f32x4*)&csum[fi] = f32x4{0.f, 0.f, 0.f, 0.f};
    }
    __syncthreads();

    // ---- phase 1: rows r0, r1 fully within this wave ----
    int r0 = i0 + 2 * wave;
    int r1 = r0 + 1;
    const u16x8* lo0p = (const u16x8*)(Glo + (size_t)r0 * B);
    const i8x8*  hi0p = (const i8x8*)(Ghi + (size_t)r0 * B);
    const u16x8* lo1p = (const u16x8*)(Glo + (size_t)r1 * B);
    const i8x8*  hi1p = (const i8x8*)(Ghi + (size_t)r1 * B);
    float m0 = -INFINITY, s0 = 0.0f, m1 = -INFINITY, s1 = 0.0f;
    #pragma unroll 2
    for (int c = 0; c < 16; ++c) {
        int vi = c * 64 + lane;          // u16x8 index within row
        u16x8 lo0 = lo0p[vi];
        i8x8  hi0 = hi0p[vi];
        u16x8 lo1 = lo1p[vi];
        i8x8  hi1 = hi1p[vi];
        f32x4 va = *(const f32x4*)&V_lds[vi * 8];
        f32x4 vb = *(const f32x4*)&V_lds[vi * 8 + 4];
        float vv[8] = {va.x, va.y, va.z, va.w, vb.x, vb.y, vb.z, vb.w};
        #pragma unroll
        for (int e = 0; e < 8; ++e) {
            int q0 = ((int)hi0[e] << 16) | (int)lo0[e];
            float v0 = fmaf((float)q0, QI, vv[e]);
            float d0 = v0 - m0;
            float E0 = __expf(-fabsf(d0));       // exp(-inf)=0 first elem
            bool n0 = d0 > 0.0f;
            s0 = n0 ? fmaf(s0, E0, 1.0f) : (s0 + E0);
            m0 = n0 ? v0 : m0;
            int q1 = ((int)hi1[e] << 16) | (int)lo1[e];
            float v1 = fmaf((float)q1, QI, vv[e]);
            float d1 = v1 - m1;
            float E1 = __expf(-fabsf(d1));
            bool n1 = d1 > 0.0f;
            s1 = n1 ? fmaf(s1, E1, 1.0f) : (s1 + E1);
            m1 = n1 ? v1 : m1;
        }
    }
    // in-wave butterfly combine of (m,s) per row -> all lanes hold result
    #pragma unroll
    for (int off = 1; off < 64; off <<= 1) {
        float mo = __shfl_xor(m0, off, 64), so = __shfl_xor(s0, off, 64);
        float m2 = fmaxf(m0, mo);
        s0 = s0 * __expf(m0 - m2) + so * __expf(mo - m2);
        m0 = m2;
        float mp = __shfl_xor(m1, off, 64), sp = __shfl_xor(s1, off, 64);
        float m3 = fmaxf(m1, mp);
        s1 = s1 * __expf(m1 - m3) + sp * __expf(mp - m3);
        m1 = m3;
    }
    float W0 = m0 + logf(s0);    // = -U[r0]; s >= 1 so finite
    float W1 = m1 + logf(s1);

    // ---- phase 2: re-read own rows (L2-hot), accumulate P into csum ----
    #pragma unroll 2
    for (int c = 0; c < 16; ++c) {
        int vi = c * 64 + lane;
        u16x8 lo0 = lo0p[vi];
        i8x8  hi0 = hi0p[vi];
        u16x8 lo1 = lo1p[vi];
        i8x8  hi1 = hi1p[vi];
        f32x4 va = *(const f32x4*)&V_lds[vi * 8];
        f32x4 vb = *(const f32x4*)&V_lds[vi * 8 + 4];
        float vv[8] = {va.x, va.y, va.z, va.w, vb.x, vb.y, vb.z, vb.w};
        float p0[8], p1[8];
        #pragma unroll
        for (int e = 0; e < 8; ++e) {
            int q0 = ((int)hi0[e] << 16) | (int)lo0[e];
            p0[e] = __expf(fmaf((float)q0, QI, vv[e]) - W0);   // P in [0,1]
            int q1 = ((int)hi1[e] << 16) | (int)lo1[e];
            p1[e] = __expf(fmaf((float)q1, QI, vv[e]) - W1);
        }
        int jb = vi * 8;
        int rot = (jb >> 6) & 7;            // = (lane>>3)&7
        // element k (col jb+k) lands at swizzled slot jb + (k^rot):
        // per step, banks get exactly 2 lanes each (free).
        #pragma unroll
        for (int k = 0; k < 8; ++k)
            atomicAdd(&csum[jb + (k ^ rot)], p0[k]);
        #pragma unroll
        for (int k = 0; k < 8; ++k)
            atomicAdd(&csum[jb + (k ^ rot)], p1[k]);
    }
    __syncthreads();

    // ---- writeout: unswizzle csum -> pm[chunk] (linear, coalesced) ----
    #pragma unroll
    for (int k = 0; k < 4; ++k) {
        int jb = 2048 * k + 4 * t;
        int rot = (jb >> 6) & 7;
        f32x4 o;
        o.x = csum[(jb + 0) ^ rot];
        o.y = csum[(jb + 1) ^ rot];
        o.z = csum[(jb + 2) ^ rot];
        o.w = csum[(jb + 3) ^ rot];
        *(f32x4*)&pm[(size_t)chunk * B + jb] = o;
    }
}

// ---------------- combine: V[j] -= log(sum of 512 chunk partials) ----------------
// 256 blocks x 256 threads; block handles 32 cols; thread (pl,g) sums 64 chunks.
__global__ __launch_bounds__(256) void col_combine(const float* __restrict__ pm) {
    int t = threadIdx.x;
    int pl = t & 31;
    int g = t >> 5;               // 0..7
    int j = blockIdx.x * 32 + pl;
    float s = 0.0f;
    #pragma unroll 8
    for (int c = g * 64; c < g * 64 + 64; ++c)
        s += pm[(size_t)c * B + j];
    __shared__ float ls[8][32];
    ls[g][pl] = s;
    __syncthreads();
    if (t < 32) {
        float s0 = ls[0][t];
        #pragma unroll
        for (int gg = 1; gg < 8; ++gg) s0 += ls[gg][t];
        int jj = blockIdx.x * 32 + t;
        // clamp: all-underflow columns get a bounded push (self-correcting)
        g_V[jj] -= logf(fmaxf(s0, 1e-30f));
    }
}

// ---------------- argmax + gather: out[i] = y[argmax_j(G[i][j]+V[j])] ----------------
__global__ __launch_bounds__(256) void argmax_out(const unsigned short* __restrict__ Glo,
                                                  const signed char* __restrict__ Ghi,
                                                  const float* __restrict__ y,
                                                  float* __restrict__ out) {
    int i = blockIdx.x;
    int t = threadIdx.x;
    const u16x8* lo8 = (const u16x8*)(Glo + (size_t)i * B);
    const i8x8*  hi8 = (const i8x8*)(Ghi + (size_t)i * B);
    const f32x4* v4 = (const f32x4*)g_V;
    float best = -INFINITY;
    int bj = 0;                              // safe init (never OOB)
    #pragma unroll
    for (int it = 0; it < 4; ++it) {
        int idx = it * 256 + t;
        u16x8 lo = lo8[idx];
        i8x8  hi = hi8[idx];
        f32x4 va = v4[idx * 2], vb = v4[idx * 2 + 1];
        float vv[8] = {va.x, va.y, va.z, va.w, vb.x, vb.y, vb.z, vb.w};
        #pragma unroll
        for (int k = 0; k < 8; ++k) {
            int q = ((int)hi[k] << 16) | (int)lo[k];
            float val = fmaf((float)q, QI, vv[k]);
            int j = idx * 8 + k;
            if (val > best) { best = val; bj = j; }
        }
    }
    __shared__ float bm[256];
    __shared__ int   bidx[256];
    bm[t] = best; bidx[t] = bj;
    __syncthreads();
    #pragma unroll
    for (int off = 128; off; off >>= 1) {
        if (t < off) {
            float om = bm[t + off]; int oj = bidx[t + off];
            if (om > bm[t] || (om == bm[t] && oj < bidx[t])) { bm[t] = om; bidx[t] = oj; }
        }
        __syncthreads();
    }
    int jstar = bidx[0];
    out[(size_t)i * C + t] = y[(size_t)jstar * C + t];
}

extern "C" void kernel_launch(void* const* d_in, const int* in_sizes, int n_in,
                              void* d_out, int out_size, void* d_ws, size_t ws_size,
                              hipStream_t stream) {
    const float* x = (const float*)d_in[0];
    const float* y = (const float*)d_in[1];
    float* out = (float*)d_out;
    unsigned short* Glo = (unsigned short*)d_ws;                           // 128 MiB
    signed char*    Ghi = (signed char*)((char*)d_ws + (size_t)B * B * 2); // +64 MiB
    float* pm = (float*)((char*)d_ws + (size_t)B * B * 3);                 // +16 MiB

    init_V<<<B / 4, 256, 0, stream>>>(y);
    gemm_G<<<dim3(B / GT, B / GT), 256, 0, stream>>>(x, y, Glo, Ghi);
    for (int l = 0; l < LITERS; ++l) {
        fused_iter<<<NCH, 512, 0, stream>>>(Glo, Ghi, pm);
        col_combine<<<B / 32, 256, 0, stream>>>(pm);
    }
    argmax_out<<<B, 256, 0, stream>>>(Glo, Ghi, y, out);
}

// Round 6
// 4929.754 us; speedup vs baseline: 7.5618x; 7.5618x over previous
//
#include <hip/hip_runtime.h>
#include <math.h>

// Sinkhorn OT layer, B=8192, C=256, L=100, LAMBD=1.
//
// U = log_u - ||x_i||^2, V = log_v - ||y_j||^2, G[i][j] = 2*dot(x_i,y_j):
//   U[i] = -LSE_j(G[i][j] + V[j]),  V[j] = -LSE_i(G[i][j] + U[i])
// init V[j] = -||y_j||^2. Final: out[i] = y[argmax_j(G[i][j]+V[j])].
//
// R6: int24 G (Glo u16 + Ghi s8). Separate passes: 7498 us (2x G read/iter).
// R7/R9: fusion via cache re-read: FAILED (L2 window spills; L3 gives no
// BW amplification). R10: fusion via LDS atomics: DISASTER (67M serialized
// DS RMW/dispatch, 412 us).
// R11: fusion with ZERO re-read and ZERO atomics. Thread t owns cols
// 16t..16t+15 for ALL rows; per 2-row window the loaded val[2][16] stays
// in REGISTERS across the block-wide row reduction:
//   load -> block max-reduce (fmax butterfly + 8-slot LDS, no exps)
//        -> e = exp(val-M) in place (the ONLY exp: 1/element)
//        -> block sum-reduce -> cs[k] += e[k]/S   (exp(val-W)=exp(val-M)/S)
// G read ONCE per iteration. 512-thr blocks, 16 rows each, 8 windows,
// 2 barriers/window, double-buffered reduce slots (write-after-read safe:
// window w+2's writes are fenced by w+1's barriers; readers of w finished
// before their own w+1 publishes). Grid 512 = 2 blocks/CU.
// Per-iter HBM: ~390 -> ~224 MiB (G 192 + pm 16w+16r).
//
// Kept: int24 G (q=2^-15, err 1.5e-5), conflict-free f32 GEMM, linear
// column sums of P=exp(G+V-W) in [0,1] (R9-validated), combine clamp
// (self-correcting), smallest-index argmax tie-break.

#define B 8192
#define C 256
#define LITERS 100
#define RPB 16                     // rows per fused block
#define NCH (B / RPB)              // 512 chunks

#define QS 65536.0f                // (2*acc) * 32768 == acc * 65536
#define QI 3.0517578125e-5f        // 2^-15

typedef float f32x4 __attribute__((ext_vector_type(4)));
typedef unsigned short u16x8 __attribute__((ext_vector_type(8)));
typedef signed char i8x8 __attribute__((ext_vector_type(8)));

__device__ __align__(16) float g_V[B];

// ---------------- init: V[j] = -||y_j||^2 ----------------
__global__ __launch_bounds__(256) void init_V(const float* __restrict__ y) {
    int wave = threadIdx.x >> 6;
    int lane = threadIdx.x & 63;
    int row = blockIdx.x * 4 + wave;
    const f32x4* yr = (const f32x4*)(y + (size_t)row * C);
    f32x4 v = yr[lane];
    float s = v.x * v.x + v.y * v.y + v.z * v.z + v.w * v.w;
    #pragma unroll
    for (int off = 32; off; off >>= 1) s += __shfl_down(s, off, 64);
    if (lane == 0) g_V[row] = -s;
}

// ---------------- GEMM: G = 2 * x @ y^T, quantized to int24 ----------------
#define GT 64
#define GKT 64
#define LSTR (GKT + 4)   // 68 floats; float4-aligned offsets

__global__ __launch_bounds__(256) void gemm_G(const float* __restrict__ x,
                                              const float* __restrict__ y,
                                              unsigned short* __restrict__ Glo,
                                              signed char* __restrict__ Ghi) {
    __shared__ float As[GT][LSTR];   // [i][k]
    __shared__ float Bs[GT][LSTR];   // [j][k]
    int bi = blockIdx.y * GT;
    int bj = blockIdx.x * GT;
    int t = threadIdx.x;
    int tx = t & 15, ty = t >> 4;
    float acc[4][4] = {};
    for (int kk = 0; kk < C; kk += GKT) {
        #pragma unroll
        for (int l = 0; l < 4; ++l) {
            int idx = t + l * 256;         // float4 index in tile
            int r = idx >> 4;              // tile row 0..63
            int c4 = idx & 15;             // float4 col 0..15
            *(f32x4*)&As[r][c4 * 4] =
                *(const f32x4*)(x + (size_t)(bi + r) * C + kk + c4 * 4);
            *(f32x4*)&Bs[r][c4 * 4] =
                *(const f32x4*)(y + (size_t)(bj + r) * C + kk + c4 * 4);
        }
        __syncthreads();
        #pragma unroll
        for (int k4 = 0; k4 < GKT / 4; ++k4) {
            f32x4 a[4], b[4];
            #pragma unroll
            for (int ii = 0; ii < 4; ++ii)
                a[ii] = *(const f32x4*)&As[ty * 4 + ii][k4 * 4];
            #pragma unroll
            for (int jj = 0; jj < 4; ++jj)
                b[jj] = *(const f32x4*)&Bs[tx + 16 * jj][k4 * 4];
            #pragma unroll
            for (int ii = 0; ii < 4; ++ii)
                #pragma unroll
                for (int jj = 0; jj < 4; ++jj) {
                    acc[ii][jj] = fmaf(a[ii].x, b[jj].x, acc[ii][jj]);
                    acc[ii][jj] = fmaf(a[ii].y, b[jj].y, acc[ii][jj]);
                    acc[ii][jj] = fmaf(a[ii].z, b[jj].z, acc[ii][jj]);
                    acc[ii][jj] = fmaf(a[ii].w, b[jj].w, acc[ii][jj]);
                }
        }
        __syncthreads();
    }
    #pragma unroll
    for (int ii = 0; ii < 4; ++ii) {
        int gi = bi + ty * 4 + ii;
        #pragma unroll
        for (int jj = 0; jj < 4; ++jj) {
            size_t idx = (size_t)gi * B + bj + tx + 16 * jj;
            float gs = acc[ii][jj] * QS;                       // G * 2^15
            gs = fminf(fmaxf(gs, -8388607.0f), 8388607.0f);    // int24 clamp
            int v = __float2int_rn(gs);
            Glo[idx] = (unsigned short)(v & 0xFFFF);
            Ghi[idx] = (signed char)(v >> 16);
        }
    }
}

// ---------------- fused row+col pass ----------------
// Block = 512 threads (8 waves), owns rows [chunk*16, chunk*16+16).
// Thread t owns cols 16t..16t+15 for every row.
__global__ __launch_bounds__(512, 4) void fused_iter(
        const unsigned short* __restrict__ Glo,
        const signed char* __restrict__ Ghi,
        float* __restrict__ pm) {
    __shared__ float wredm[2][2][8];   // [buf][row][wave]
    __shared__ float wreds[2][2][8];
    int t = threadIdx.x;
    int chunk = blockIdx.x;
    int i0 = chunk * RPB;
    int wave = t >> 6, lane = t & 63;

    // this thread's 16 V values (constant across the dispatch)
    float vreg[16];
    #pragma unroll
    for (int q = 0; q < 4; ++q) {
        f32x4 v = *(const f32x4*)&g_V[16 * t + 4 * q];
        vreg[4 * q + 0] = v.x; vreg[4 * q + 1] = v.y;
        vreg[4 * q + 2] = v.z; vreg[4 * q + 3] = v.w;
    }
    float cs[16];
    #pragma unroll
    for (int k = 0; k < 16; ++k) cs[k] = 0.0f;

    for (int w = 0; w < RPB / 2; ++w) {
        int buf = w & 1;
        int ra = i0 + 2 * w;
        int rb = ra + 1;
        // ---- load both rows' 16 cols: val = G + V ----
        float val0[16], val1[16];
        {
            const u16x8* lop = (const u16x8*)(Glo + (size_t)ra * B);
            const i8x8*  hip = (const i8x8*)(Ghi + (size_t)ra * B);
            u16x8 a0 = lop[2 * t], a1 = lop[2 * t + 1];
            i8x8  b0 = hip[2 * t], b1 = hip[2 * t + 1];
            #pragma unroll
            for (int e = 0; e < 8; ++e) {
                int q0 = ((int)b0[e] << 16) | (int)a0[e];
                val0[e] = fmaf((float)q0, QI, vreg[e]);
                int q1 = ((int)b1[e] << 16) | (int)a1[e];
                val0[8 + e] = fmaf((float)q1, QI, vreg[8 + e]);
            }
        }
        {
            const u16x8* lop = (const u16x8*)(Glo + (size_t)rb * B);
            const i8x8*  hip = (const i8x8*)(Ghi + (size_t)rb * B);
            u16x8 a0 = lop[2 * t], a1 = lop[2 * t + 1];
            i8x8  b0 = hip[2 * t], b1 = hip[2 * t + 1];
            #pragma unroll
            for (int e = 0; e < 8; ++e) {
                int q0 = ((int)b0[e] << 16) | (int)a0[e];
                val1[e] = fmaf((float)q0, QI, vreg[e]);
                int q1 = ((int)b1[e] << 16) | (int)a1[e];
                val1[8 + e] = fmaf((float)q1, QI, vreg[8 + e]);
            }
        }
        // ---- block max-reduce (no exps) ----
        float M0 = val0[0], M1 = val1[0];
        #pragma unroll
        for (int k = 1; k < 16; ++k) {
            M0 = fmaxf(M0, val0[k]);
            M1 = fmaxf(M1, val1[k]);
        }
        #pragma unroll
        for (int off = 1; off < 64; off <<= 1) {
            M0 = fmaxf(M0, __shfl_xor(M0, off, 64));
            M1 = fmaxf(M1, __shfl_xor(M1, off, 64));
        }
        if (lane == 0) { wredm[buf][0][wave] = M0; wredm[buf][1][wave] = M1; }
        __syncthreads();
        M0 = wredm[buf][0][0];
        M1 = wredm[buf][1][0];
        #pragma unroll
        for (int k = 1; k < 8; ++k) {
            M0 = fmaxf(M0, wredm[buf][0][k]);
            M1 = fmaxf(M1, wredm[buf][1][k]);
        }
        // ---- e = exp(val - M) in place; block sum-reduce ----
        float s0 = 0.0f, s1 = 0.0f;
        #pragma unroll
        for (int k = 0; k < 16; ++k) {
            val0[k] = __expf(val0[k] - M0); s0 += val0[k];
            val1[k] = __expf(val1[k] - M1); s1 += val1[k];
        }
        #pragma unroll
        for (int off = 1; off < 64; off <<= 1) {
            s0 += __shfl_xor(s0, off, 64);
            s1 += __shfl_xor(s1, off, 64);
        }
        if (lane == 0) { wreds[buf][0][wave] = s0; wreds[buf][1][wave] = s1; }
        __syncthreads();
        s0 = wreds[buf][0][0];
        s1 = wreds[buf][1][0];
        #pragma unroll
        for (int k = 1; k < 8; ++k) {
            s0 += wreds[buf][0][k];
            s1 += wreds[buf][1][k];
        }
        // ---- column accumulate: cs += e/S (= exp(val - W), in [0,1]) ----
        float inv0 = 1.0f / s0, inv1 = 1.0f / s1;
        #pragma unroll
        for (int k = 0; k < 16; ++k) {
            cs[k] = fmaf(val0[k], inv0, cs[k]);
            cs[k] = fmaf(val1[k], inv1, cs[k]);
        }
    }
    // ---- writeout ----
    #pragma unroll
    for (int q = 0; q < 4; ++q) {
        f32x4 o = {cs[4 * q + 0], cs[4 * q + 1], cs[4 * q + 2], cs[4 * q + 3]};
        *(f32x4*)&pm[(size_t)chunk * B + 16 * t + 4 * q] = o;
    }
}

// ---------------- combine: V[j] -= log(sum of 512 chunk partials) ----------------
__global__ __launch_bounds__(256) void col_combine(const float* __restrict__ pm) {
    int t = threadIdx.x;
    int pl = t & 31;
    int g = t >> 5;               // 0..7
    int j = blockIdx.x * 32 + pl;
    float s = 0.0f;
    #pragma unroll 8
    for (int c = g * 64; c < g * 64 + 64; ++c)
        s += pm[(size_t)c * B + j];
    __shared__ float ls[8][32];
    ls[g][pl] = s;
    __syncthreads();
    if (t < 32) {
        float s0 = ls[0][t];
        #pragma unroll
        for (int gg = 1; gg < 8; ++gg) s0 += ls[gg][t];
        int jj = blockIdx.x * 32 + t;
        // clamp: all-underflow columns get a bounded push (self-correcting)
        g_V[jj] -= logf(fmaxf(s0, 1e-30f));
    }
}

// ---------------- argmax + gather: out[i] = y[argmax_j(G[i][j]+V[j])] ----------------
__global__ __launch_bounds__(256) void argmax_out(const unsigned short* __restrict__ Glo,
                                                  const signed char* __restrict__ Ghi,
                                                  const float* __restrict__ y,
                                                  float* __restrict__ out) {
    int i = blockIdx.x;
    int t = threadIdx.x;
    const u16x8* lo8 = (const u16x8*)(Glo + (size_t)i * B);
    const i8x8*  hi8 = (const i8x8*)(Ghi + (size_t)i * B);
    const f32x4* v4 = (const f32x4*)g_V;
    float best = -INFINITY;
    int bj = 0;                              // safe init (never OOB)
    #pragma unroll
    for (int it = 0; it < 4; ++it) {
        int idx = it * 256 + t;
        u16x8 lo = lo8[idx];
        i8x8  hi = hi8[idx];
        f32x4 va = v4[idx * 2], vb = v4[idx * 2 + 1];
        float vv[8] = {va.x, va.y, va.z, va.w, vb.x, vb.y, vb.z, vb.w};
        #pragma unroll
        for (int k = 0; k < 8; ++k) {
            int q = ((int)hi[k] << 16) | (int)lo[k];
            float val = fmaf((float)q, QI, vv[k]);
            int j = idx * 8 + k;
            if (val > best) { best = val; bj = j; }
        }
    }
    __shared__ float bm[256];
    __shared__ int   bidx[256];
    bm[t] = best; bidx[t] = bj;
    __syncthreads();
    #pragma unroll
    for (int off = 128; off; off >>= 1) {
        if (t < off) {
            float om = bm[t + off]; int oj = bidx[t + off];
            if (om > bm[t] || (om == bm[t] && oj < bidx[t])) { bm[t] = om; bidx[t] = oj; }
        }
        __syncthreads();
    }
    int jstar = bidx[0];
    out[(size_t)i * C + t] = y[(size_t)jstar * C + t];
}

extern "C" void kernel_launch(void* const* d_in, const int* in_sizes, int n_in,
                              void* d_out, int out_size, void* d_ws, size_t ws_size,
                              hipStream_t stream) {
    const float* x = (const float*)d_in[0];
    const float* y = (const float*)d_in[1];
    float* out = (float*)d_out;
    unsigned short* Glo = (unsigned short*)d_ws;                           // 128 MiB
    signed char*    Ghi = (signed char*)((char*)d_ws + (size_t)B * B * 2); // +64 MiB
    float* pm = (float*)((char*)d_ws + (size_t)B * B * 3);                 // +16 MiB

    init_V<<<B / 4, 256, 0, stream>>>(y);
    gemm_G<<<dim3(B / GT, B / GT), 256, 0, stream>>>(x, y, Glo, Ghi);
    for (int l = 0; l < LITERS; ++l) {
        fused_iter<<<NCH, 512, 0, stream>>>(Glo, Ghi, pm);
        col_combine<<<B / 32, 256, 0, stream>>>(pm);
    }
    argmax_out<<<B, 256, 0, stream>>>(Glo, Ghi, y, out);
}